// Round 26
// baseline (1397.909 us; speedup 1.0000x reference)
//
#include <hip/hip_runtime.h>

#define NN 50000
#define NE 800000
#define D  128
#define RT 32
#define NB 196                     // ceil(NN/256): scan blocks
#define ND ((size_t)NN * D)
#define RNG 6250                   // NN/8: dst-range width (one range per XCD)

typedef unsigned short u16;
typedef unsigned int   u32;
typedef long long      ll64;

__device__ __forceinline__ float bf2f(u16 v) {
  return __uint_as_float(((u32)v) << 16);
}
__device__ __forceinline__ u16 f2bf(float f) {
  u32 u = __float_as_uint(f);
  u32 r = u + 0x7fffu + ((u >> 16) & 1u);   // RNE
  return (u16)(r >> 16);
}
__device__ __forceinline__ float bflo(u32 u) { return __uint_as_float(u << 16); }
__device__ __forceinline__ float bfhi(u32 u) { return __uint_as_float(u & 0xffff0000u); }
__device__ __forceinline__ float ldf(const void* p, size_t i, int isf32) {
  return isf32 ? ((const float*)p)[i] : bf2f(((const u16*)p)[i]);
}
__device__ __forceinline__ int lde(const void* p, size_t i, int isi64) {
  return isi64 ? (int)((const ll64*)p)[i] : ((const int*)p)[i];
}

// flags: [0]=floats-are-f32, [1]=edges-are-i64
__global__ void k_detect(const void* __restrict__ feat, const void* __restrict__ edges,
                         int* __restrict__ flags) {
  __shared__ int cnt0, cnt1;
  int t = threadIdx.x;
  if (t == 0) { cnt0 = 0; cnt1 = 0; }
  __syncthreads();
  float v = ((const float*)feat)[t];
  float av = fabsf(v);
  if (av == 0.f || (av >= 1e-8f && av <= 1e4f)) atomicAdd(&cnt0, 1);
  if (t < 128) {
    if (((const int*)edges)[2 * t + 1] != 0) atomicAdd(&cnt1, 1);
  }
  __syncthreads();
  if (t == 0) {
    flags[0] = (cnt0 >= 240) ? 1 : 0;
    flags[1] = (cnt1 == 0) ? 1 : 0;
  }
}

// ---- ws-too-small sentinel (f32 out) ----
__global__ void k_sent(float* __restrict__ out, int n) {
  int i = blockIdx.x * 256 + threadIdx.x;
  if (i < n) out[i] = 3000.0f;
}

// ---- init: out[k] = features (f32 state), all 4 relations ----
__global__ void k_init(const void* __restrict__ feat, float* __restrict__ out,
                       const int* __restrict__ flags) {
  int isf32 = flags[0];
  int k = blockIdx.y;
  size_t i = (size_t)blockIdx.x * 256 + threadIdx.x;   // float4 index in slice
  float4 v;
  if (isf32) {
    v = ((const float4*)feat)[i];
  } else {
    uint2 u = ((const uint2*)feat)[i];
    v = make_float4(bflo(u.x), bfhi(u.x), bflo(u.y), bfhi(u.y));
  }
  ((float4*)out)[(size_t)k * (ND / 4) + i] = v;
}

// ---- pack edges once: epack[k][e] = src | dst<<16 (both < 50000 < 65536) ----
__global__ void k_conv(const void* __restrict__ edges, u32* __restrict__ epack,
                       const int* __restrict__ flags) {
  int isi64 = flags[1];
  int k = blockIdx.y;
  int e = blockIdx.x * 256 + threadIdx.x;
  int src = lde(edges, (size_t)k * 2 * NE + e, isi64);
  int dst = lde(edges, (size_t)k * 2 * NE + NE + e, isi64);
  epack[(size_t)k * NE + e] = (u32)src | ((u32)dst << 16);
}

// -------- CSR build: dst-range-partitioned (8 ranges == 8 XCDs), packed edges --------
__global__ void k_count(const u32* __restrict__ epack, int* __restrict__ deg) {
  int bid = blockIdx.x;
  int r8 = bid & 7;
  int k = (bid >> 3) & 3;
  int e = (bid >> 5) * 256 + threadIdx.x;
  int dst = (int)(epack[(size_t)k * NE + e] >> 16);
  if (dst / RNG == r8) atomicAdd(&deg[k * NN + dst], 1);
}

__global__ void k_bsum(const int* __restrict__ deg, int* __restrict__ bsum) {
  int k = blockIdx.y, b = blockIdx.x, t = threadIdx.x;
  __shared__ int sh[256];
  int idx = b * 256 + t;
  sh[t] = (idx < NN) ? deg[k * NN + idx] : 0;
  __syncthreads();
  for (int off = 128; off; off >>= 1) {
    if (t < off) sh[t] += sh[t + off];
    __syncthreads();
  }
  if (t == 0) bsum[k * NB + b] = sh[0];
}

__global__ void k_bscan(const int* __restrict__ bsum, int* __restrict__ boff) {
  __shared__ int sh[256];
  int t = threadIdx.x;
  for (int k = 0; k < 4; k++) {
    int v = (t < NB) ? bsum[k * NB + t] : 0;
    sh[t] = v;
    __syncthreads();
    for (int off = 1; off < 256; off <<= 1) {
      int a = (t >= off) ? sh[t - off] : 0;
      __syncthreads();
      sh[t] += a;
      __syncthreads();
    }
    if (t < NB) boff[k * NB + t] = sh[t] - v;   // exclusive
    __syncthreads();
  }
}

__global__ void k_place(const int* __restrict__ deg, const int* __restrict__ boff,
                        int* __restrict__ rowp, int* __restrict__ cur) {
  int k = blockIdx.y, b = blockIdx.x, t = threadIdx.x;
  __shared__ int sh[256];
  int idx = b * 256 + t;
  int v = (idx < NN) ? deg[k * NN + idx] : 0;
  sh[t] = v;
  __syncthreads();
  for (int off = 1; off < 256; off <<= 1) {
    int a = (t >= off) ? sh[t - off] : 0;
    __syncthreads();
    sh[t] += a;
    __syncthreads();
  }
  int incl = boff[k * NB + b] + sh[t];
  if (idx < NN) {
    rowp[(size_t)k * (NN + 1) + idx + 1] = incl;
    cur[k * NN + idx] = incl - v;
  }
  if (b == 0 && t == 0) rowp[(size_t)k * (NN + 1)] = 0;
}

__global__ void k_scatter(const u32* __restrict__ epack, int* __restrict__ cur,
                          u16* __restrict__ colx) {
  int bid = blockIdx.x;
  int r8 = bid & 7;
  int k = (bid >> 3) & 3;
  int e = (bid >> 5) * 256 + threadIdx.x;
  u32 v = epack[(size_t)k * NE + e];
  int dst = (int)(v >> 16);
  if (dst / RNG == r8) {
    int pos = atomicAdd(&cur[k * NN + dst], 1);
    colx[(size_t)k * NE + pos] = (u16)(v & 0xffffu);
  }
}

// ---- prep (batched): Bm[k] = diag(rel_k)@W_l; asf/adf[k]; zero stat partials[k] ----
__global__ void k_prep(const void* __restrict__ gatW, const void* __restrict__ asrc,
                       const void* __restrict__ adst, const void* __restrict__ rel_emb,
                       const float* __restrict__ relc, int layer,
                       float* __restrict__ Bm, float* __restrict__ asf, float* __restrict__ adf,
                       float* __restrict__ colsum, float* __restrict__ colsq,
                       const int* __restrict__ flags) {
  int isf32 = flags[0];
  int k = blockIdx.x;
  int r = threadIdx.x;
  float rv = (layer == 0) ? ldf(rel_emb, (size_t)k * D + r, isf32) : relc[k * D + r];
  size_t Wo = (size_t)layer * D * D + (size_t)r * D;
  float* Bk = Bm + (size_t)k * D * D;
  for (int c = 0; c < D; c++)
    Bk[r * D + c] = rv * ldf(gatW, Wo + c, isf32);
  asf[k * D + r] = ldf(asrc, (size_t)layer * D + r, isf32);
  adf[k * D + r] = ldf(adst, (size_t)layer * D + r, isf32);
  #pragma unroll
  for (int i = 0; i < 8; i++) {
    colsum[((size_t)k * 8 + i) * D + r] = 0.f;
    colsq[((size_t)k * 8 + i) * D + r] = 0.f;
  }
}

// ------- GEMM (batched): hb[k](bf16 rows) = x_k @ Bm[k]; alpha via half-wave reduce -------
__launch_bounds__(256)
__global__ void k_gemm(const float* __restrict__ xbase, const float* __restrict__ Bm,
                       const float* __restrict__ asf, const float* __restrict__ adf,
                       u32* __restrict__ hb, float* __restrict__ av_s, float* __restrict__ av_d) {
  int k = blockIdx.y;
  const float* x = xbase + (size_t)k * ND;
  const float* Bk = Bm + (size_t)k * D * D;
  u32* hbk = hb + (size_t)k * NN * 64;

  __shared__ float xl[RT * D];     // 16 KB
  int t = threadIdx.x;
  int row0 = blockIdx.x * RT;

  for (int i = t; i < RT * D / 4; i += 256) {
    int r = i >> 5;
    int row = row0 + r;
    float4 v = make_float4(0.f, 0.f, 0.f, 0.f);
    if (row < NN) v = ((const float4*)(x + (size_t)row * D))[i & 31];
    ((float4*)xl)[i] = v;
  }
  __syncthreads();

  int cg = t & 31, rg = t >> 5;
  float acc0[4], acc1[4], acc2[4], acc3[4];
  #pragma unroll
  for (int j = 0; j < 4; j++) { acc0[j] = 0; acc1[j] = 0; acc2[j] = 0; acc3[j] = 0; }
  const float* Bp = Bk + cg * 4;
  const float* xp = xl + (rg * 4) * D;
  for (int kk = 0; kk < D; kk += 4) {
    float4 b0 = *(const float4*)(Bp + (kk    ) * D);
    float4 b1 = *(const float4*)(Bp + (kk + 1) * D);
    float4 b2 = *(const float4*)(Bp + (kk + 2) * D);
    float4 b3 = *(const float4*)(Bp + (kk + 3) * D);
    #pragma unroll
    for (int j = 0; j < 4; j++) {
      float4 x4 = *(const float4*)(xp + j * D + kk);
      acc0[j] += x4.x * b0.x + x4.y * b1.x + x4.z * b2.x + x4.w * b3.x;
      acc1[j] += x4.x * b0.y + x4.y * b1.y + x4.z * b2.y + x4.w * b3.y;
      acc2[j] += x4.x * b0.z + x4.y * b1.z + x4.z * b2.z + x4.w * b3.z;
      acc3[j] += x4.x * b0.w + x4.y * b1.w + x4.z * b2.w + x4.w * b3.w;
    }
  }
  #pragma unroll
  for (int j = 0; j < 4; j++) {
    int row = row0 + rg * 4 + j;
    if (row < NN) {
      uint2 pk;
      pk.x = (u32)f2bf(acc0[j]) | ((u32)f2bf(acc1[j]) << 16);
      pk.y = (u32)f2bf(acc2[j]) | ((u32)f2bf(acc3[j]) << 16);
      *(uint2*)(hbk + (size_t)row * 64 + cg * 2) = pk;
    }
  }
  float w0 = asf[k * D + cg * 4], w1 = asf[k * D + cg * 4 + 1],
        w2 = asf[k * D + cg * 4 + 2], w3 = asf[k * D + cg * 4 + 3];
  float u0 = adf[k * D + cg * 4], u1 = adf[k * D + cg * 4 + 1],
        u2 = adf[k * D + cg * 4 + 2], u3 = adf[k * D + cg * 4 + 3];
  #pragma unroll
  for (int j = 0; j < 4; j++) {
    float ps = acc0[j] * w0 + acc1[j] * w1 + acc2[j] * w2 + acc3[j] * w3;
    float pd = acc0[j] * u0 + acc1[j] * u1 + acc2[j] * u2 + acc3[j] * u3;
    #pragma unroll
    for (int off = 16; off; off >>= 1) {
      ps += __shfl_xor(ps, off, 32);
      pd += __shfl_xor(pd, off, 32);
    }
    int row = row0 + rg * 4 + j;
    if (cg == 0 && row < NN) {
      av_s[(size_t)k * NN + row] = ps;
      av_d[(size_t)k * NN + row] = pd;
    }
  }
}

// ------- fused aggregation: 8 edges/iter (8-lane groups), XCD-pinned + BN stats -------
__launch_bounds__(256)
__global__ void k_aggf(const int* __restrict__ rowp, const u16* __restrict__ colx,
                       const float* __restrict__ av_s, const float* __restrict__ av_d,
                       const u32* __restrict__ hb, const void* __restrict__ gatb,
                       int layer, u32* __restrict__ tmpw, float* __restrict__ outf,
                       float* __restrict__ colsum, float* __restrict__ colsq,
                       const int* __restrict__ flags) {
  int isf32 = flags[0];
  int bid = blockIdx.x;
  int xcd = bid & 7;
  int k = xcd >> 1;
  int widx = ((bid >> 3) << 1) | (xcd & 1);   // block index within relation k, [0,12500)
  int wv = threadIdx.x >> 6;
  int n = widx * 4 + wv;
  int lane = threadIdx.x & 63;
  int o = lane >> 3;           // which edge of the octet this 8-lane group handles
  int cl8 = lane & 7;          // 16-col segment index within the row
  const int* rp = rowp + (size_t)k * (NN + 1);
  int s0 = rp[n], s1 = rp[n + 1];
  int deg = s1 - s0;
  const float* avs = av_s + (size_t)k * NN;
  float ad = av_d[(size_t)k * NN + n];
  const u16* cl = colx + (size_t)k * NE;
  const uint4* h4 = (const uint4*)(hb + (size_t)k * NN * 64);   // row = 16 uint4

  int src0 = 0; float e0 = -INFINITY;
  if (lane < deg) {
    src0 = (int)cl[s0 + lane];
    float e = avs[src0] + ad;
    e0 = e > 0.f ? e : 0.2f * e;
  }
  float m = e0;
  for (int base = 64; base < deg; base += 64) {
    int j = base + lane;
    if (j < deg) {
      int s = (int)cl[s0 + j];
      float e = avs[s] + ad;
      e = e > 0.f ? e : 0.2f * e;
      m = fmaxf(m, e);
    }
  }
  #pragma unroll
  for (int off = 32; off; off >>= 1) m = fmaxf(m, __shfl_xor(m, off, 64));

  float p0 = (lane < deg) ? __expf(e0 - m) : 0.f;
  float den = p0;
  float a[16];
  #pragma unroll
  for (int i = 0; i < 16; i++) a[i] = 0.f;
  {
    int cnt = min(64, deg);
    int iters = (cnt + 7) >> 3;            // wave-uniform; jidx = 8*it+o <= 63
    for (int it = 0; it < iters; it++) {
      int jidx = 8 * it + o;
      float ps = __shfl(p0, jidx, 64);     // 0 beyond deg -> contribution vanishes
      int   ss = __shfl(src0, jidx, 64);
      uint4 h0 = h4[(size_t)ss * 16 + cl8 * 2];
      uint4 h1 = h4[(size_t)ss * 16 + cl8 * 2 + 1];
      a[0] += ps * bflo(h0.x);  a[1] += ps * bfhi(h0.x);
      a[2] += ps * bflo(h0.y);  a[3] += ps * bfhi(h0.y);
      a[4] += ps * bflo(h0.z);  a[5] += ps * bfhi(h0.z);
      a[6] += ps * bflo(h0.w);  a[7] += ps * bfhi(h0.w);
      a[8] += ps * bflo(h1.x);  a[9] += ps * bfhi(h1.x);
      a[10] += ps * bflo(h1.y); a[11] += ps * bfhi(h1.y);
      a[12] += ps * bflo(h1.z); a[13] += ps * bfhi(h1.z);
      a[14] += ps * bflo(h1.w); a[15] += ps * bfhi(h1.w);
    }
  }
  for (int base = 64; base < deg; base += 64) {   // rare overflow chunks
    int j = base + lane;
    int srcx = 0; float px = 0.f;
    if (j < deg) {
      srcx = (int)cl[s0 + j];
      float e = avs[srcx] + ad;
      e = e > 0.f ? e : 0.2f * e;
      px = __expf(e - m);
    }
    den += px;
    int cnt = min(64, deg - base);
    int iters = (cnt + 7) >> 3;
    for (int it = 0; it < iters; it++) {
      int jidx = 8 * it + o;
      float ps = __shfl(px, jidx, 64);
      int   ss = __shfl(srcx, jidx, 64);
      uint4 h0 = h4[(size_t)ss * 16 + cl8 * 2];
      uint4 h1 = h4[(size_t)ss * 16 + cl8 * 2 + 1];
      a[0] += ps * bflo(h0.x);  a[1] += ps * bfhi(h0.x);
      a[2] += ps * bflo(h0.y);  a[3] += ps * bfhi(h0.y);
      a[4] += ps * bflo(h0.z);  a[5] += ps * bfhi(h0.z);
      a[6] += ps * bflo(h0.w);  a[7] += ps * bfhi(h0.w);
      a[8] += ps * bflo(h1.x);  a[9] += ps * bfhi(h1.x);
      a[10] += ps * bflo(h1.y); a[11] += ps * bfhi(h1.y);
      a[12] += ps * bflo(h1.z); a[13] += ps * bfhi(h1.z);
      a[14] += ps * bflo(h1.w); a[15] += ps * bfhi(h1.w);
    }
  }
  #pragma unroll
  for (int off = 32; off; off >>= 1) den += __shfl_xor(den, off, 64);
  float di = 1.f / (den + 1e-16f);

  // fold the 8 edge-groups (same columns): lanes differ in bits 3,4,5
  #pragma unroll
  for (int i = 0; i < 16; i++) {
    a[i] += __shfl_xor(a[i], 8, 64);
    a[i] += __shfl_xor(a[i], 16, 64);
    a[i] += __shfl_xor(a[i], 32, 64);
  }

  __shared__ float ps_[4][D], pq_[4][D];
  if (o == 0) {
    int c = cl8 * 16;
    float ov[16];
    #pragma unroll
    for (int i = 0; i < 16; i++)
      ov[i] = a[i] * di + ldf(gatb, (size_t)layer * D + c + i, isf32);
    if (tmpw) {
      uint4 pk0, pk1;
      pk0.x = (u32)f2bf(ov[0]) | ((u32)f2bf(ov[1]) << 16);
      pk0.y = (u32)f2bf(ov[2]) | ((u32)f2bf(ov[3]) << 16);
      pk0.z = (u32)f2bf(ov[4]) | ((u32)f2bf(ov[5]) << 16);
      pk0.w = (u32)f2bf(ov[6]) | ((u32)f2bf(ov[7]) << 16);
      pk1.x = (u32)f2bf(ov[8]) | ((u32)f2bf(ov[9]) << 16);
      pk1.y = (u32)f2bf(ov[10]) | ((u32)f2bf(ov[11]) << 16);
      pk1.z = (u32)f2bf(ov[12]) | ((u32)f2bf(ov[13]) << 16);
      pk1.w = (u32)f2bf(ov[14]) | ((u32)f2bf(ov[15]) << 16);
      u32* tp = tmpw + (size_t)k * NN * 64 + (size_t)n * 64 + cl8 * 8;
      *(uint4*)tp = pk0;
      *(uint4*)(tp + 4) = pk1;
    } else {
      float* op = outf + (size_t)k * ND + (size_t)n * D + c;
      *(float4*)op = make_float4(ov[0], ov[1], ov[2], ov[3]);
      *(float4*)(op + 4) = make_float4(ov[4], ov[5], ov[6], ov[7]);
      *(float4*)(op + 8) = make_float4(ov[8], ov[9], ov[10], ov[11]);
      *(float4*)(op + 12) = make_float4(ov[12], ov[13], ov[14], ov[15]);
    }
    if (colsum) {
      #pragma unroll
      for (int i = 0; i < 16; i++) {
        ps_[wv][c + i] = ov[i];
        pq_[wv][c + i] = ov[i] * ov[i];
      }
    }
  }
  if (colsum) {
    __syncthreads();
    int t = threadIdx.x;
    if (t < D) {
      size_t slot = ((size_t)k * 8 + (widx & 7)) * D + t;
      atomicAdd(&colsum[slot], ps_[0][t] + ps_[1][t] + ps_[2][t] + ps_[3][t]);
      atomicAdd(&colsq[slot],  pq_[0][t] + pq_[1][t] + pq_[2][t] + pq_[3][t]);
    }
  }
}

// ---- BN finalize: fold 8 partials -> mu, rsig (tiny) ----
__global__ void k_bnfin(const float* __restrict__ colsum, const float* __restrict__ colsq,
                        float* __restrict__ mu, float* __restrict__ rsig) {
  int k = blockIdx.x;
  int c = threadIdx.x;
  const float* csk = colsum + (size_t)k * 8 * D;
  const float* cqk = colsq + (size_t)k * 8 * D;
  float cs = 0.f, cq = 0.f;
  #pragma unroll
  for (int r = 0; r < 8; r++) { cs += csk[r * D + c]; cq += cqk[r * D + c]; }
  float m = cs * (1.f / NN);
  float var = cq * (1.f / NN) - m * m;
  mu[k * D + c] = m;
  rsig[k * D + c] = rsqrtf(fmaxf(var, 0.f) + 1e-5f);
}

// ---------------- residual update: pure streaming, params staged in LDS ----------------
__global__ void k_update(float* __restrict__ e, const u32* __restrict__ tmpw,
                         const float* __restrict__ mu, const float* __restrict__ rsig,
                         const void* __restrict__ gamma, const void* __restrict__ beta,
                         int layer, const int* __restrict__ flags) {
  int isf32 = flags[0];
  int k = blockIdx.y;
  __shared__ float smu[D], srs[D], sg[D], sb[D];
  int t = threadIdx.x;
  if (t < D) {
    smu[t] = mu[k * D + t];
    srs[t] = rsig[k * D + t];
    sg[t] = ldf(gamma, (size_t)layer * D + t, isf32);
    sb[t] = ldf(beta, (size_t)layer * D + t, isf32);
  }
  __syncthreads();
  size_t idx = (size_t)blockIdx.x * 256 + t;   // float4 index in slice
  int c0 = ((int)(idx & 31)) * 4;
  uint2 tv = *(const uint2*)(tmpw + (size_t)k * NN * 64 + idx * 2);
  float tb[4] = {bflo(tv.x), bfhi(tv.x), bflo(tv.y), bfhi(tv.y)};
  float* ek = e + (size_t)k * ND;
  float4 e4 = ((const float4*)ek)[idx];
  float eb[4] = {e4.x, e4.y, e4.z, e4.w};
  #pragma unroll
  for (int i = 0; i < 4; i++) {
    int c = c0 + i;
    float bn = sg[c] * (tb[i] - smu[c]) * srs[c] + sb[c];
    bn = bn > 0.f ? bn : 0.01f * bn;
    eb[i] += bn;
  }
  ((float4*)ek)[idx] = make_float4(eb[0], eb[1], eb[2], eb[3]);
}

// ---------------- rel update (batched); final layer -> out tail ----------------
__global__ void k_relup(const void* __restrict__ relW, const void* __restrict__ relb,
                        const void* __restrict__ rel_emb, float* __restrict__ relc,
                        int layer, float* __restrict__ out_final,
                        const int* __restrict__ flags) {
  int isf32 = flags[0];
  int k = blockIdx.x;
  __shared__ float rl[D];
  int c = threadIdx.x;
  rl[c] = (layer == 0) ? ldf(rel_emb, (size_t)k * D + c, isf32) : relc[k * D + c];
  __syncthreads();
  float acc = ldf(relb, (size_t)layer * D + c, isf32);
  size_t Wo = ((size_t)layer * D + c) * D;
  for (int kk = 0; kk < D; kk++) acc += ldf(relW, Wo + kk, isf32) * rl[kk];
  relc[k * D + c] = acc;
  if (out_final) out_final[(size_t)k * D + c] = acc;
}

extern "C" void kernel_launch(void* const* d_in, const int* in_sizes, int n_in,
                              void* d_out, int out_size, void* d_ws, size_t ws_size,
                              hipStream_t stream) {
  const void* feat    = d_in[0];
  const void* rel_emb = d_in[1];
  const void* edges   = d_in[2];
  const void* gatW    = d_in[3];
  const void* asrc    = d_in[4];
  const void* adst    = d_in[5];
  const void* gatb    = d_in[6];
  const void* gamma   = d_in[7];
  const void* beta    = d_in[8];
  const void* relW    = d_in[9];
  const void* relb    = d_in[10];
  float* out = (float*)d_out;     // f32: [4][NN][D] emb state + [4][D] rel tail

  char* p = (char*)d_ws;
  auto take = [&](size_t bytes) -> void* {
    void* r = (void*)p;
    p += (bytes + 255) & ~(size_t)255;
    return r;
  };
  u32*   hb     = (u32*)  take((size_t)4 * NN * 64 * 4);   // 51.2 MB: per-k bf16 h rows
  u32*   tmpw   = (u32*)  take((size_t)4 * NN * 64 * 4);   // 51.2 MB: per-k bf16 agg out
  u32*   epack  = (u32*)  take((size_t)4 * NE * 4);        // 12.8 MB: packed src|dst
  u16*   colx   = (u16*)  take((size_t)4 * NE * 2);        // 6.4 MB
  int*   rowp   = (int*)  take((size_t)4 * (NN + 1) * 4);
  int*   cur    = (int*)  take((size_t)4 * NN * 4);
  int*   deg    = (int*)  take((size_t)4 * NN * 4);
  int*   bsum   = (int*)  take((size_t)4 * NB * 4);
  int*   boff   = (int*)  take((size_t)4 * NB * 4);
  float* av_s   = (float*)take((size_t)4 * NN * 4);
  float* av_d   = (float*)take((size_t)4 * NN * 4);
  float* Bm     = (float*)take((size_t)4 * D * D * 4);
  float* asf    = (float*)take(4 * D * 4);
  float* adf    = (float*)take(4 * D * 4);
  float* relc   = (float*)take(4 * D * 4);
  float* colsum = (float*)take((size_t)4 * 8 * D * 4);
  float* colsq  = (float*)take((size_t)4 * 8 * D * 4);
  float* muv    = (float*)take(4 * D * 4);
  float* rsv    = (float*)take(4 * D * 4);
  int*   flags  = (int*)  take(64);

  size_t need = (size_t)(p - (char*)d_ws);
  if (ws_size < need) {
    k_sent<<<(out_size + 255) / 256, 256, 0, stream>>>(out, out_size);
    return;
  }

  hipMemsetAsync(deg, 0, (size_t)4 * NN * 4, stream);

  k_detect<<<1, 256, 0, stream>>>(feat, edges, flags);
  k_init<<<dim3((int)(ND / 4 / 256), 4), 256, 0, stream>>>(feat, out, flags);
  k_conv<<<dim3(NE / 256, 4), 256, 0, stream>>>(edges, epack, flags);
  k_count<<<(NE / 256) * 32, 256, 0, stream>>>(epack, deg);
  k_bsum<<<dim3(NB, 4), 256, 0, stream>>>(deg, bsum);
  k_bscan<<<1, 256, 0, stream>>>(bsum, boff);
  k_place<<<dim3(NB, 4), 256, 0, stream>>>(deg, boff, rowp, cur);
  k_scatter<<<(NE / 256) * 32, 256, 0, stream>>>(epack, cur, colx);

  for (int layer = 0; layer < 3; layer++) {
    bool last = (layer == 2);
    k_prep<<<4, 128, 0, stream>>>(gatW, asrc, adst, rel_emb, relc, layer,
                                  Bm, asf, adf, colsum, colsq, flags);
    k_gemm<<<dim3((NN + RT - 1) / RT, 4), 256, 0, stream>>>(out, Bm, asf, adf, hb, av_s, av_d);
    if (!last) {
      k_aggf<<<NN, 256, 0, stream>>>(rowp, colx, av_s, av_d, hb, gatb, layer,
                                     tmpw, (float*)nullptr, colsum, colsq, flags);
      k_bnfin<<<4, 128, 0, stream>>>(colsum, colsq, muv, rsv);
      k_update<<<dim3((int)(ND / 4 / 256), 4), 256, 0, stream>>>(out, tmpw, muv, rsv,
                                                                 gamma, beta, layer, flags);
      k_relup<<<4, 128, 0, stream>>>(relW, relb, rel_emb, relc, layer, (float*)nullptr, flags);
    } else {
      k_aggf<<<NN, 256, 0, stream>>>(rowp, colx, av_s, av_d, hb, gatb, layer,
                                     (u32*)nullptr, out, (float*)nullptr, (float*)nullptr, flags);
      k_relup<<<4, 128, 0, stream>>>(relW, relb, rel_emb, relc, layer, out + 4 * ND, flags);
    }
  }
}

// Round 27
// 1310.911 us; speedup vs baseline: 1.0664x; 1.0664x over previous
//
#include <hip/hip_runtime.h>

#define NN 50000
#define NE 800000
#define D  128
#define RT 32
#define NB 196                     // ceil(NN/256): scan blocks
#define ND ((size_t)NN * D)
#define RNG 6250                   // NN/8: dst-range width (one range per XCD)

typedef unsigned short u16;
typedef unsigned int   u32;
typedef long long      ll64;

__device__ __forceinline__ float bf2f(u16 v) {
  return __uint_as_float(((u32)v) << 16);
}
__device__ __forceinline__ u16 f2bf(float f) {
  u32 u = __float_as_uint(f);
  u32 r = u + 0x7fffu + ((u >> 16) & 1u);   // RNE
  return (u16)(r >> 16);
}
__device__ __forceinline__ float bflo(u32 u) { return __uint_as_float(u << 16); }
__device__ __forceinline__ float bfhi(u32 u) { return __uint_as_float(u & 0xffff0000u); }
__device__ __forceinline__ float ldf(const void* p, size_t i, int isf32) {
  return isf32 ? ((const float*)p)[i] : bf2f(((const u16*)p)[i]);
}
__device__ __forceinline__ int lde(const void* p, size_t i, int isi64) {
  return isi64 ? (int)((const ll64*)p)[i] : ((const int*)p)[i];
}

// flags: [0]=floats-are-f32, [1]=edges-are-i64
__global__ void k_detect(const void* __restrict__ feat, const void* __restrict__ edges,
                         int* __restrict__ flags) {
  __shared__ int cnt0, cnt1;
  int t = threadIdx.x;
  if (t == 0) { cnt0 = 0; cnt1 = 0; }
  __syncthreads();
  float v = ((const float*)feat)[t];
  float av = fabsf(v);
  if (av == 0.f || (av >= 1e-8f && av <= 1e4f)) atomicAdd(&cnt0, 1);
  if (t < 128) {
    if (((const int*)edges)[2 * t + 1] != 0) atomicAdd(&cnt1, 1);
  }
  __syncthreads();
  if (t == 0) {
    flags[0] = (cnt0 >= 240) ? 1 : 0;
    flags[1] = (cnt1 == 0) ? 1 : 0;
  }
}

// ---- ws-too-small sentinel (f32 out) ----
__global__ void k_sent(float* __restrict__ out, int n) {
  int i = blockIdx.x * 256 + threadIdx.x;
  if (i < n) out[i] = 3000.0f;
}

// ---- init: out[k] = features (f32 state), all 4 relations ----
__global__ void k_init(const void* __restrict__ feat, float* __restrict__ out,
                       const int* __restrict__ flags) {
  int isf32 = flags[0];
  int k = blockIdx.y;
  size_t i = (size_t)blockIdx.x * 256 + threadIdx.x;   // float4 index in slice
  float4 v;
  if (isf32) {
    v = ((const float4*)feat)[i];
  } else {
    uint2 u = ((const uint2*)feat)[i];
    v = make_float4(bflo(u.x), bfhi(u.x), bflo(u.y), bfhi(u.y));
  }
  ((float4*)out)[(size_t)k * (ND / 4) + i] = v;
}

// ---- pack edges once: epack[k][e] = src | dst<<16 (both < 50000 < 65536) ----
__global__ void k_conv(const void* __restrict__ edges, u32* __restrict__ epack,
                       const int* __restrict__ flags) {
  int isi64 = flags[1];
  int k = blockIdx.y;
  int e = blockIdx.x * 256 + threadIdx.x;
  int src = lde(edges, (size_t)k * 2 * NE + e, isi64);
  int dst = lde(edges, (size_t)k * 2 * NE + NE + e, isi64);
  epack[(size_t)k * NE + e] = (u32)src | ((u32)dst << 16);
}

// -------- CSR build: dst-range-partitioned (8 ranges == 8 XCDs), packed edges --------
__global__ void k_count(const u32* __restrict__ epack, int* __restrict__ deg) {
  int bid = blockIdx.x;
  int r8 = bid & 7;
  int k = (bid >> 3) & 3;
  int e = (bid >> 5) * 256 + threadIdx.x;
  int dst = (int)(epack[(size_t)k * NE + e] >> 16);
  if (dst / RNG == r8) atomicAdd(&deg[k * NN + dst], 1);
}

__global__ void k_bsum(const int* __restrict__ deg, int* __restrict__ bsum) {
  int k = blockIdx.y, b = blockIdx.x, t = threadIdx.x;
  __shared__ int sh[256];
  int idx = b * 256 + t;
  sh[t] = (idx < NN) ? deg[k * NN + idx] : 0;
  __syncthreads();
  for (int off = 128; off; off >>= 1) {
    if (t < off) sh[t] += sh[t + off];
    __syncthreads();
  }
  if (t == 0) bsum[k * NB + b] = sh[0];
}

__global__ void k_bscan(const int* __restrict__ bsum, int* __restrict__ boff) {
  __shared__ int sh[256];
  int t = threadIdx.x;
  for (int k = 0; k < 4; k++) {
    int v = (t < NB) ? bsum[k * NB + t] : 0;
    sh[t] = v;
    __syncthreads();
    for (int off = 1; off < 256; off <<= 1) {
      int a = (t >= off) ? sh[t - off] : 0;
      __syncthreads();
      sh[t] += a;
      __syncthreads();
    }
    if (t < NB) boff[k * NB + t] = sh[t] - v;   // exclusive
    __syncthreads();
  }
}

__global__ void k_place(const int* __restrict__ deg, const int* __restrict__ boff,
                        int* __restrict__ rowp, int* __restrict__ cur) {
  int k = blockIdx.y, b = blockIdx.x, t = threadIdx.x;
  __shared__ int sh[256];
  int idx = b * 256 + t;
  int v = (idx < NN) ? deg[k * NN + idx] : 0;
  sh[t] = v;
  __syncthreads();
  for (int off = 1; off < 256; off <<= 1) {
    int a = (t >= off) ? sh[t - off] : 0;
    __syncthreads();
    sh[t] += a;
    __syncthreads();
  }
  int incl = boff[k * NB + b] + sh[t];
  if (idx < NN) {
    rowp[(size_t)k * (NN + 1) + idx + 1] = incl;
    cur[k * NN + idx] = incl - v;
  }
  if (b == 0 && t == 0) rowp[(size_t)k * (NN + 1)] = 0;
}

__global__ void k_scatter(const u32* __restrict__ epack, int* __restrict__ cur,
                          u16* __restrict__ colx) {
  int bid = blockIdx.x;
  int r8 = bid & 7;
  int k = (bid >> 3) & 3;
  int e = (bid >> 5) * 256 + threadIdx.x;
  u32 v = epack[(size_t)k * NE + e];
  int dst = (int)(v >> 16);
  if (dst / RNG == r8) {
    int pos = atomicAdd(&cur[k * NN + dst], 1);
    colx[(size_t)k * NE + pos] = (u16)(v & 0xffffu);
  }
}

// ---- prep (batched): Bm[k] = diag(rel_k)@W_l; asf/adf[k]; zero stat partials[k] ----
__global__ void k_prep(const void* __restrict__ gatW, const void* __restrict__ asrc,
                       const void* __restrict__ adst, const void* __restrict__ rel_emb,
                       const float* __restrict__ relc, int layer,
                       float* __restrict__ Bm, float* __restrict__ asf, float* __restrict__ adf,
                       float* __restrict__ colsum, float* __restrict__ colsq,
                       const int* __restrict__ flags) {
  int isf32 = flags[0];
  int k = blockIdx.x;
  int r = threadIdx.x;
  float rv = (layer == 0) ? ldf(rel_emb, (size_t)k * D + r, isf32) : relc[k * D + r];
  size_t Wo = (size_t)layer * D * D + (size_t)r * D;
  float* Bk = Bm + (size_t)k * D * D;
  for (int c = 0; c < D; c++)
    Bk[r * D + c] = rv * ldf(gatW, Wo + c, isf32);
  asf[k * D + r] = ldf(asrc, (size_t)layer * D + r, isf32);
  adf[k * D + r] = ldf(adst, (size_t)layer * D + r, isf32);
  #pragma unroll
  for (int i = 0; i < 8; i++) {
    colsum[((size_t)k * 8 + i) * D + r] = 0.f;
    colsq[((size_t)k * 8 + i) * D + r] = 0.f;
  }
}

// ------- GEMM (batched): hb[k](bf16 rows) = x_k @ Bm[k]; alpha via half-wave reduce -------
__launch_bounds__(256)
__global__ void k_gemm(const float* __restrict__ xbase, const float* __restrict__ Bm,
                       const float* __restrict__ asf, const float* __restrict__ adf,
                       u32* __restrict__ hb, float* __restrict__ av_s, float* __restrict__ av_d) {
  int k = blockIdx.y;
  const float* x = xbase + (size_t)k * ND;
  const float* Bk = Bm + (size_t)k * D * D;
  u32* hbk = hb + (size_t)k * NN * 64;

  __shared__ float xl[RT * D];     // 16 KB
  int t = threadIdx.x;
  int row0 = blockIdx.x * RT;

  for (int i = t; i < RT * D / 4; i += 256) {
    int r = i >> 5;
    int row = row0 + r;
    float4 v = make_float4(0.f, 0.f, 0.f, 0.f);
    if (row < NN) v = ((const float4*)(x + (size_t)row * D))[i & 31];
    ((float4*)xl)[i] = v;
  }
  __syncthreads();

  int cg = t & 31, rg = t >> 5;
  float acc0[4], acc1[4], acc2[4], acc3[4];
  #pragma unroll
  for (int j = 0; j < 4; j++) { acc0[j] = 0; acc1[j] = 0; acc2[j] = 0; acc3[j] = 0; }
  const float* Bp = Bk + cg * 4;
  const float* xp = xl + (rg * 4) * D;
  for (int kk = 0; kk < D; kk += 4) {
    float4 b0 = *(const float4*)(Bp + (kk    ) * D);
    float4 b1 = *(const float4*)(Bp + (kk + 1) * D);
    float4 b2 = *(const float4*)(Bp + (kk + 2) * D);
    float4 b3 = *(const float4*)(Bp + (kk + 3) * D);
    #pragma unroll
    for (int j = 0; j < 4; j++) {
      float4 x4 = *(const float4*)(xp + j * D + kk);
      acc0[j] += x4.x * b0.x + x4.y * b1.x + x4.z * b2.x + x4.w * b3.x;
      acc1[j] += x4.x * b0.y + x4.y * b1.y + x4.z * b2.y + x4.w * b3.y;
      acc2[j] += x4.x * b0.z + x4.y * b1.z + x4.z * b2.z + x4.w * b3.z;
      acc3[j] += x4.x * b0.w + x4.y * b1.w + x4.z * b2.w + x4.w * b3.w;
    }
  }
  #pragma unroll
  for (int j = 0; j < 4; j++) {
    int row = row0 + rg * 4 + j;
    if (row < NN) {
      uint2 pk;
      pk.x = (u32)f2bf(acc0[j]) | ((u32)f2bf(acc1[j]) << 16);
      pk.y = (u32)f2bf(acc2[j]) | ((u32)f2bf(acc3[j]) << 16);
      *(uint2*)(hbk + (size_t)row * 64 + cg * 2) = pk;
    }
  }
  float w0 = asf[k * D + cg * 4], w1 = asf[k * D + cg * 4 + 1],
        w2 = asf[k * D + cg * 4 + 2], w3 = asf[k * D + cg * 4 + 3];
  float u0 = adf[k * D + cg * 4], u1 = adf[k * D + cg * 4 + 1],
        u2 = adf[k * D + cg * 4 + 2], u3 = adf[k * D + cg * 4 + 3];
  #pragma unroll
  for (int j = 0; j < 4; j++) {
    float ps = acc0[j] * w0 + acc1[j] * w1 + acc2[j] * w2 + acc3[j] * w3;
    float pd = acc0[j] * u0 + acc1[j] * u1 + acc2[j] * u2 + acc3[j] * u3;
    #pragma unroll
    for (int off = 16; off; off >>= 1) {
      ps += __shfl_xor(ps, off, 32);
      pd += __shfl_xor(pd, off, 32);
    }
    int row = row0 + rg * 4 + j;
    if (cg == 0 && row < NN) {
      av_s[(size_t)k * NN + row] = ps;
      av_d[(size_t)k * NN + row] = pd;
    }
  }
}

// ------- fused aggregation: 4 edges/iter (quarter-wave each), XCD-pinned + BN stats -------
__launch_bounds__(256)
__global__ void k_aggf(const int* __restrict__ rowp, const u16* __restrict__ colx,
                       const float* __restrict__ av_s, const float* __restrict__ av_d,
                       const u32* __restrict__ hb, const void* __restrict__ gatb,
                       int layer, u32* __restrict__ tmpw, float* __restrict__ outf,
                       float* __restrict__ colsum, float* __restrict__ colsq,
                       const int* __restrict__ flags) {
  int isf32 = flags[0];
  int bid = blockIdx.x;
  int xcd = bid & 7;
  int k = xcd >> 1;
  int widx = ((bid >> 3) << 1) | (xcd & 1);   // block index within relation k, [0,12500)
  int wv = threadIdx.x >> 6;
  int n = widx * 4 + wv;
  int lane = threadIdx.x & 63;
  int q = lane >> 4;           // which edge of the quad this quarter-wave handles
  int cl16 = lane & 15;        // uint4 (8-col) index within the row
  const int* rp = rowp + (size_t)k * (NN + 1);
  int s0 = rp[n], s1 = rp[n + 1];
  int deg = s1 - s0;
  const float* avs = av_s + (size_t)k * NN;
  float ad = av_d[(size_t)k * NN + n];
  const u16* cl = colx + (size_t)k * NE;
  const uint4* h4 = (const uint4*)(hb + (size_t)k * NN * 64);   // row = 16 uint4

  int src0 = 0; float e0 = -INFINITY;
  if (lane < deg) {
    src0 = (int)cl[s0 + lane];
    float e = avs[src0] + ad;
    e0 = e > 0.f ? e : 0.2f * e;
  }
  float m = e0;
  for (int base = 64; base < deg; base += 64) {
    int j = base + lane;
    if (j < deg) {
      int s = (int)cl[s0 + j];
      float e = avs[s] + ad;
      e = e > 0.f ? e : 0.2f * e;
      m = fmaxf(m, e);
    }
  }
  #pragma unroll
  for (int off = 32; off; off >>= 1) m = fmaxf(m, __shfl_xor(m, off, 64));

  float p0 = (lane < deg) ? __expf(e0 - m) : 0.f;
  float den = p0;
  float a0 = 0.f, a1 = 0.f, a2 = 0.f, a3 = 0.f;
  float a4 = 0.f, a5 = 0.f, a6 = 0.f, a7 = 0.f;
  {
    int cnt = min(64, deg);
    int iters = (cnt + 3) >> 2;            // wave-uniform; jidx = 4*it+q <= 63
    for (int it = 0; it < iters; it++) {
      int jidx = 4 * it + q;
      float ps = __shfl(p0, jidx, 64);     // 0 beyond deg -> contribution vanishes
      int   ss = __shfl(src0, jidx, 64);
      uint4 hv = h4[(size_t)ss * 16 + cl16];
      a0 += ps * bflo(hv.x); a1 += ps * bfhi(hv.x);
      a2 += ps * bflo(hv.y); a3 += ps * bfhi(hv.y);
      a4 += ps * bflo(hv.z); a5 += ps * bfhi(hv.z);
      a6 += ps * bflo(hv.w); a7 += ps * bfhi(hv.w);
    }
  }
  for (int base = 64; base < deg; base += 64) {   // rare overflow chunks
    int j = base + lane;
    int srcx = 0; float px = 0.f;
    if (j < deg) {
      srcx = (int)cl[s0 + j];
      float e = avs[srcx] + ad;
      e = e > 0.f ? e : 0.2f * e;
      px = __expf(e - m);
    }
    den += px;
    int cnt = min(64, deg - base);
    int iters = (cnt + 3) >> 2;
    for (int it = 0; it < iters; it++) {
      int jidx = 4 * it + q;
      float ps = __shfl(px, jidx, 64);
      int   ss = __shfl(srcx, jidx, 64);
      uint4 hv = h4[(size_t)ss * 16 + cl16];
      a0 += ps * bflo(hv.x); a1 += ps * bfhi(hv.x);
      a2 += ps * bflo(hv.y); a3 += ps * bfhi(hv.y);
      a4 += ps * bflo(hv.z); a5 += ps * bfhi(hv.z);
      a6 += ps * bflo(hv.w); a7 += ps * bfhi(hv.w);
    }
  }
  #pragma unroll
  for (int off = 32; off; off >>= 1) den += __shfl_xor(den, off, 64);
  float di = 1.f / (den + 1e-16f);

  // fold the 4 quarter-waves (same columns, different edge subsets): lanes differ in bits 4,5
  a0 += __shfl_xor(a0, 16, 64); a0 += __shfl_xor(a0, 32, 64);
  a1 += __shfl_xor(a1, 16, 64); a1 += __shfl_xor(a1, 32, 64);
  a2 += __shfl_xor(a2, 16, 64); a2 += __shfl_xor(a2, 32, 64);
  a3 += __shfl_xor(a3, 16, 64); a3 += __shfl_xor(a3, 32, 64);
  a4 += __shfl_xor(a4, 16, 64); a4 += __shfl_xor(a4, 32, 64);
  a5 += __shfl_xor(a5, 16, 64); a5 += __shfl_xor(a5, 32, 64);
  a6 += __shfl_xor(a6, 16, 64); a6 += __shfl_xor(a6, 32, 64);
  a7 += __shfl_xor(a7, 16, 64); a7 += __shfl_xor(a7, 32, 64);

  __shared__ float ps_[4][D], pq_[4][D];
  if (q == 0) {
    int c = cl16 * 8;
    float o0 = a0 * di + ldf(gatb, (size_t)layer * D + c, isf32);
    float o1 = a1 * di + ldf(gatb, (size_t)layer * D + c + 1, isf32);
    float o2 = a2 * di + ldf(gatb, (size_t)layer * D + c + 2, isf32);
    float o3 = a3 * di + ldf(gatb, (size_t)layer * D + c + 3, isf32);
    float o4 = a4 * di + ldf(gatb, (size_t)layer * D + c + 4, isf32);
    float o5 = a5 * di + ldf(gatb, (size_t)layer * D + c + 5, isf32);
    float o6 = a6 * di + ldf(gatb, (size_t)layer * D + c + 6, isf32);
    float o7 = a7 * di + ldf(gatb, (size_t)layer * D + c + 7, isf32);
    if (tmpw) {
      uint4 pk;
      pk.x = (u32)f2bf(o0) | ((u32)f2bf(o1) << 16);
      pk.y = (u32)f2bf(o2) | ((u32)f2bf(o3) << 16);
      pk.z = (u32)f2bf(o4) | ((u32)f2bf(o5) << 16);
      pk.w = (u32)f2bf(o6) | ((u32)f2bf(o7) << 16);
      *(uint4*)(tmpw + (size_t)k * NN * 64 + (size_t)n * 64 + cl16 * 4) = pk;
    } else {
      float* op = outf + (size_t)k * ND + (size_t)n * D + c;
      *(float4*)op = make_float4(o0, o1, o2, o3);
      *(float4*)(op + 4) = make_float4(o4, o5, o6, o7);
    }
    if (colsum) {
      ps_[wv][c] = o0;      ps_[wv][c + 1] = o1;
      ps_[wv][c + 2] = o2;  ps_[wv][c + 3] = o3;
      ps_[wv][c + 4] = o4;  ps_[wv][c + 5] = o5;
      ps_[wv][c + 6] = o6;  ps_[wv][c + 7] = o7;
      pq_[wv][c] = o0 * o0;     pq_[wv][c + 1] = o1 * o1;
      pq_[wv][c + 2] = o2 * o2; pq_[wv][c + 3] = o3 * o3;
      pq_[wv][c + 4] = o4 * o4; pq_[wv][c + 5] = o5 * o5;
      pq_[wv][c + 6] = o6 * o6; pq_[wv][c + 7] = o7 * o7;
    }
  }
  if (colsum) {
    __syncthreads();
    int t = threadIdx.x;
    if (t < D) {
      size_t slot = ((size_t)k * 8 + (widx & 7)) * D + t;
      atomicAdd(&colsum[slot], ps_[0][t] + ps_[1][t] + ps_[2][t] + ps_[3][t]);
      atomicAdd(&colsq[slot],  pq_[0][t] + pq_[1][t] + pq_[2][t] + pq_[3][t]);
    }
  }
}

// ---- BN finalize: fold 8 partials -> mu, rsig (tiny) ----
__global__ void k_bnfin(const float* __restrict__ colsum, const float* __restrict__ colsq,
                        float* __restrict__ mu, float* __restrict__ rsig) {
  int k = blockIdx.x;
  int c = threadIdx.x;
  const float* csk = colsum + (size_t)k * 8 * D;
  const float* cqk = colsq + (size_t)k * 8 * D;
  float cs = 0.f, cq = 0.f;
  #pragma unroll
  for (int r = 0; r < 8; r++) { cs += csk[r * D + c]; cq += cqk[r * D + c]; }
  float m = cs * (1.f / NN);
  float var = cq * (1.f / NN) - m * m;
  mu[k * D + c] = m;
  rsig[k * D + c] = rsqrtf(fmaxf(var, 0.f) + 1e-5f);
}

// ---------------- residual update: pure streaming, params staged in LDS ----------------
__global__ void k_update(float* __restrict__ e, const u32* __restrict__ tmpw,
                         const float* __restrict__ mu, const float* __restrict__ rsig,
                         const void* __restrict__ gamma, const void* __restrict__ beta,
                         int layer, const int* __restrict__ flags) {
  int isf32 = flags[0];
  int k = blockIdx.y;
  __shared__ float smu[D], srs[D], sg[D], sb[D];
  int t = threadIdx.x;
  if (t < D) {
    smu[t] = mu[k * D + t];
    srs[t] = rsig[k * D + t];
    sg[t] = ldf(gamma, (size_t)layer * D + t, isf32);
    sb[t] = ldf(beta, (size_t)layer * D + t, isf32);
  }
  __syncthreads();
  size_t idx = (size_t)blockIdx.x * 256 + t;   // float4 index in slice
  int c0 = ((int)(idx & 31)) * 4;
  uint2 tv = *(const uint2*)(tmpw + (size_t)k * NN * 64 + idx * 2);
  float tb[4] = {bflo(tv.x), bfhi(tv.x), bflo(tv.y), bfhi(tv.y)};
  float* ek = e + (size_t)k * ND;
  float4 e4 = ((const float4*)ek)[idx];
  float eb[4] = {e4.x, e4.y, e4.z, e4.w};
  #pragma unroll
  for (int i = 0; i < 4; i++) {
    int c = c0 + i;
    float bn = sg[c] * (tb[i] - smu[c]) * srs[c] + sb[c];
    bn = bn > 0.f ? bn : 0.01f * bn;
    eb[i] += bn;
  }
  ((float4*)ek)[idx] = make_float4(eb[0], eb[1], eb[2], eb[3]);
}

// ---------------- rel update (batched); final layer -> out tail ----------------
__global__ void k_relup(const void* __restrict__ relW, const void* __restrict__ relb,
                        const void* __restrict__ rel_emb, float* __restrict__ relc,
                        int layer, float* __restrict__ out_final,
                        const int* __restrict__ flags) {
  int isf32 = flags[0];
  int k = blockIdx.x;
  __shared__ float rl[D];
  int c = threadIdx.x;
  rl[c] = (layer == 0) ? ldf(rel_emb, (size_t)k * D + c, isf32) : relc[k * D + c];
  __syncthreads();
  float acc = ldf(relb, (size_t)layer * D + c, isf32);
  size_t Wo = ((size_t)layer * D + c) * D;
  for (int kk = 0; kk < D; kk++) acc += ldf(relW, Wo + kk, isf32) * rl[kk];
  relc[k * D + c] = acc;
  if (out_final) out_final[(size_t)k * D + c] = acc;
}

extern "C" void kernel_launch(void* const* d_in, const int* in_sizes, int n_in,
                              void* d_out, int out_size, void* d_ws, size_t ws_size,
                              hipStream_t stream) {
  const void* feat    = d_in[0];
  const void* rel_emb = d_in[1];
  const void* edges   = d_in[2];
  const void* gatW    = d_in[3];
  const void* asrc    = d_in[4];
  const void* adst    = d_in[5];
  const void* gatb    = d_in[6];
  const void* gamma   = d_in[7];
  const void* beta    = d_in[8];
  const void* relW    = d_in[9];
  const void* relb    = d_in[10];
  float* out = (float*)d_out;     // f32: [4][NN][D] emb state + [4][D] rel tail

  char* p = (char*)d_ws;
  auto take = [&](size_t bytes) -> void* {
    void* r = (void*)p;
    p += (bytes + 255) & ~(size_t)255;
    return r;
  };
  u32*   hb     = (u32*)  take((size_t)4 * NN * 64 * 4);   // 51.2 MB: per-k bf16 h rows
  u32*   tmpw   = (u32*)  take((size_t)4 * NN * 64 * 4);   // 51.2 MB: per-k bf16 agg out
  u32*   epack  = (u32*)  take((size_t)4 * NE * 4);        // 12.8 MB: packed src|dst
  u16*   colx   = (u16*)  take((size_t)4 * NE * 2);        // 6.4 MB
  int*   rowp   = (int*)  take((size_t)4 * (NN + 1) * 4);
  int*   cur    = (int*)  take((size_t)4 * NN * 4);
  int*   deg    = (int*)  take((size_t)4 * NN * 4);
  int*   bsum   = (int*)  take((size_t)4 * NB * 4);
  int*   boff   = (int*)  take((size_t)4 * NB * 4);
  float* av_s   = (float*)take((size_t)4 * NN * 4);
  float* av_d   = (float*)take((size_t)4 * NN * 4);
  float* Bm     = (float*)take((size_t)4 * D * D * 4);
  float* asf    = (float*)take(4 * D * 4);
  float* adf    = (float*)take(4 * D * 4);
  float* relc   = (float*)take(4 * D * 4);
  float* colsum = (float*)take((size_t)4 * 8 * D * 4);
  float* colsq  = (float*)take((size_t)4 * 8 * D * 4);
  float* muv    = (float*)take(4 * D * 4);
  float* rsv    = (float*)take(4 * D * 4);
  int*   flags  = (int*)  take(64);

  size_t need = (size_t)(p - (char*)d_ws);
  if (ws_size < need) {
    k_sent<<<(out_size + 255) / 256, 256, 0, stream>>>(out, out_size);
    return;
  }

  hipMemsetAsync(deg, 0, (size_t)4 * NN * 4, stream);

  k_detect<<<1, 256, 0, stream>>>(feat, edges, flags);
  k_init<<<dim3((int)(ND / 4 / 256), 4), 256, 0, stream>>>(feat, out, flags);
  k_conv<<<dim3(NE / 256, 4), 256, 0, stream>>>(edges, epack, flags);
  k_count<<<(NE / 256) * 32, 256, 0, stream>>>(epack, deg);
  k_bsum<<<dim3(NB, 4), 256, 0, stream>>>(deg, bsum);
  k_bscan<<<1, 256, 0, stream>>>(bsum, boff);
  k_place<<<dim3(NB, 4), 256, 0, stream>>>(deg, boff, rowp, cur);
  k_scatter<<<(NE / 256) * 32, 256, 0, stream>>>(epack, cur, colx);

  for (int layer = 0; layer < 3; layer++) {
    bool last = (layer == 2);
    k_prep<<<4, 128, 0, stream>>>(gatW, asrc, adst, rel_emb, relc, layer,
                                  Bm, asf, adf, colsum, colsq, flags);
    k_gemm<<<dim3((NN + RT - 1) / RT, 4), 256, 0, stream>>>(out, Bm, asf, adf, hb, av_s, av_d);
    if (!last) {
      k_aggf<<<NN, 256, 0, stream>>>(rowp, colx, av_s, av_d, hb, gatb, layer,
                                     tmpw, (float*)nullptr, colsum, colsq, flags);
      k_bnfin<<<4, 128, 0, stream>>>(colsum, colsq, muv, rsv);
      k_update<<<dim3((int)(ND / 4 / 256), 4), 256, 0, stream>>>(out, tmpw, muv, rsv,
                                                                 gamma, beta, layer, flags);
      k_relup<<<4, 128, 0, stream>>>(relW, relb, rel_emb, relc, layer, (float*)nullptr, flags);
    } else {
      k_aggf<<<NN, 256, 0, stream>>>(rowp, colx, av_s, av_d, hb, gatb, layer,
                                     (u32*)nullptr, out, (float*)nullptr, (float*)nullptr, flags);
      k_relup<<<4, 128, 0, stream>>>(relW, relb, rel_emb, relc, layer, out + 4 * ND, flags);
    }
  }
}